// Round 7
// baseline (264.623 us; speedup 1.0000x reference)
//
#include <hip/hip_runtime.h>
#include <hip/hip_bf16.h>

// Problem: B=8, T=4096, D=64, K=1024. N = B*T = 32768 rows.
// Inputs:  d_in[0] = x (f32, 2097152), d_in[1] = embeddings (f32, [D][K] = 64x1024)
// Output: FLOAT32, concatenated in return order:
//   quantized (2097152) | encodings (33554432) | indices (32768) | loss (1)

#define NROWS 32768
#define DDIM  64
#define KCB   1024
#define NSEG  8
#define SEG   128        // codes per K-segment

typedef float f32x4 __attribute__((ext_vector_type(4)));

// ws layout (float index):
#define WS_ET    0        // Et [K][D] transposed embeddings (65536 f32)
#define WS_H     65536    // 0.5*||e_k||^2 (1024)
#define WS_PART  66560    // per-block loss partials (2048 f32)
#define WS_PBEST 68608    // per-(seg,row) best score (8*32768 f32)
#define WS_PIDX  330752   // per-(seg,row) best index (8*32768 u16 = 131072 f32)
// end: 461824 f32 = 1.85 MB

// K1: transpose E (D,K) -> Et (K,D), h[k] = 0.5*||e_k||^2.
__global__ __launch_bounds__(256) void k1_prep(const float* __restrict__ E,
                                               float* __restrict__ Et,
                                               float* __restrict__ h) {
  int k = blockIdx.x * 256 + threadIdx.x;   // 0..1023
  float col[DDIM];
  float sum = 0.f;
#pragma unroll
  for (int d = 0; d < DDIM; ++d) {
    float v = E[d * KCB + k];               // coalesced across lanes
    col[d] = v;
    sum = fmaf(v, v, sum);
  }
  float4* dst = (float4*)(Et + (size_t)k * DDIM);
#pragma unroll
  for (int i = 0; i < 16; ++i)
    dst[i] = make_float4(col[4*i], col[4*i+1], col[4*i+2], col[4*i+3]);
  h[k] = 0.5f * sum;
}

// K2: per (row-pair, K-segment) partial argmax of score = x.e_k - 0.5||e_k||^2.
// E-segment in LDS (32KB, uniform broadcast reads). TWO rows per thread: each
// 16B LDS read feeds 8 FMAs. 512 blocks = 64 row-blocks x 8 segments.
__global__ __launch_bounds__(256, 2) void k2_score(const float* __restrict__ x,
                                                   const float* __restrict__ Et,
                                                   const float* __restrict__ h,
                                                   float* __restrict__ pbest,
                                                   unsigned short* __restrict__ pidx) {
  __shared__ float se[SEG * DDIM];   // 32 KB E-tile [k][d]
  __shared__ float sh[SEG];

  int bid = blockIdx.x;              // 0..511
  int ks  = bid >> 6;                // segment 0..7 (64 consecutive blocks share seg)
  int tid = threadIdx.x;
  int n0  = (bid & 63) * 512 + tid;  // row A; row B = n0 + 256

  // cooperative stage: 2048 float4, 8 per thread, coalesced
  {
    const float4* src = (const float4*)(Et + (size_t)ks * SEG * DDIM);
    float4* dst = (float4*)se;
#pragma unroll
    for (int i = 0; i < 8; ++i) dst[tid + i * 256] = src[tid + i * 256];
    if (tid < SEG) sh[tid] = h[ks * SEG + tid];
  }

  // two x rows -> 128 VGPRs; pin them before the barrier
  const float4* xra = (const float4*)(x + (size_t)n0 * DDIM);
  const float4* xrb = (const float4*)(x + (size_t)(n0 + 256) * DDIM);
  float4 xa[16], xb[16];
#pragma unroll
  for (int i = 0; i < 16; ++i) { xa[i] = xra[i]; xb[i] = xrb[i]; }
#pragma unroll
  for (int i = 0; i < 16; ++i) {
    asm volatile("" :: "v"(xa[i].x), "v"(xa[i].y), "v"(xa[i].z), "v"(xa[i].w));
    asm volatile("" :: "v"(xb[i].x), "v"(xb[i].y), "v"(xb[i].z), "v"(xb[i].w));
  }
  __syncthreads();

  float bestA = -3.0e38f, bestB = -3.0e38f;
  int ia = ks * SEG, ib = ks * SEG;

#pragma unroll 1
  for (int kg = 0; kg < SEG; kg += 4) {
    float accA[4], accB[4];
#pragma unroll
    for (int j = 0; j < 4; ++j) { float hn = -sh[kg + j]; accA[j] = hn; accB[j] = hn; }
#pragma unroll
    for (int i = 0; i < 16; ++i) {
      float4 xia = xa[i], xib = xb[i];
#pragma unroll
      for (int j = 0; j < 4; ++j) {
        float4 e4 = *(const float4*)(se + (kg + j) * DDIM + i * 4);  // uniform broadcast
        accA[j] = fmaf(xia.x, e4.x, accA[j]);
        accA[j] = fmaf(xia.y, e4.y, accA[j]);
        accA[j] = fmaf(xia.z, e4.z, accA[j]);
        accA[j] = fmaf(xia.w, e4.w, accA[j]);
        accB[j] = fmaf(xib.x, e4.x, accB[j]);
        accB[j] = fmaf(xib.y, e4.y, accB[j]);
        accB[j] = fmaf(xib.z, e4.z, accB[j]);
        accB[j] = fmaf(xib.w, e4.w, accB[j]);
      }
    }
#pragma unroll
    for (int j = 0; j < 4; ++j) {   // strict >: first-occurrence max wins
      if (accA[j] > bestA) { bestA = accA[j]; ia = ks * SEG + kg + j; }
      if (accB[j] > bestB) { bestB = accB[j]; ib = ks * SEG + kg + j; }
    }
  }
  pbest[ks * NROWS + n0]       = bestA;
  pidx [ks * NROWS + n0]       = (unsigned short)ia;
  pbest[ks * NROWS + n0 + 256] = bestB;
  pidx [ks * NROWS + n0 + 256] = (unsigned short)ib;
}

// K34 fused: combine segments -> index (16 rows/block); indices, quantized
// (1 float4/thread, coalesced), loss partial (plain store), one-hot stream.
__global__ __launch_bounds__(256) void k34_fused(const float* __restrict__ x,
                                                 const float* __restrict__ Et,
                                                 const float* __restrict__ pbest,
                                                 const unsigned short* __restrict__ pidx,
                                                 float* __restrict__ partial,
                                                 float* __restrict__ out_q,
                                                 float* __restrict__ out_enc,
                                                 float* __restrict__ out_ind) {
  __shared__ int sidx[16];
  int tid = threadIdx.x;
  int r0 = blockIdx.x * 16;

  if (tid < 16) {
    int n = r0 + tid;
    float best = pbest[n];
    int bi = pidx[n];
#pragma unroll
    for (int q = 1; q < NSEG; ++q) {          // ascending segs: first-occurrence ties
      float b = pbest[q * NROWS + n];
      int i2 = (int)pidx[q * NROWS + n];
      if (b > best) { best = b; bi = i2; }
    }
    sidx[tid] = bi;
    out_ind[n] = (float)bi;
  }
  __syncthreads();

  // quantized gather + loss: thread covers row r0+(tid>>4), dims [4*(tid&15), +4)
  int r = tid >> 4, c = tid & 15;
  int n = r0 + r;
  int bi = sidx[r];
  float4 q4 = *(const float4*)(Et + (size_t)bi * DDIM + c * 4);   // L2-resident gather
  float4 x4 = *(const float4*)(x + (size_t)n * DDIM + c * 4);     // coalesced
  float d0 = q4.x - x4.x, d1 = q4.y - x4.y, d2 = q4.z - x4.z, d3 = q4.w - x4.w;
  float lsum = 0.f;
  lsum = fmaf(d0, d0, lsum); lsum = fmaf(d1, d1, lsum);
  lsum = fmaf(d2, d2, lsum); lsum = fmaf(d3, d3, lsum);
  *(float4*)(out_q + (size_t)n * DDIM + c * 4) = q4;

  // one-hot encodings: thread t covers cols [4t, 4t+4) of each of 16 rows
#pragma unroll
  for (int rr = 0; rr < 16; ++rr) {
    int bk = sidx[rr];
    f32x4 v = (f32x4)(0.f);
    if ((bk >> 2) == tid) v[bk & 3] = 1.0f;
    __builtin_nontemporal_store(v, (f32x4*)(out_enc + (size_t)(r0 + rr) * KCB + tid * 4));
  }

  // block loss reduction -> plain store
#pragma unroll
  for (int off = 32; off > 0; off >>= 1) lsum += __shfl_down(lsum, off);
  __shared__ float red[4];
  int lane = tid & 63, w = tid >> 6;
  if (lane == 0) red[w] = lsum;
  __syncthreads();
  if (tid == 0) partial[blockIdx.x] = red[0] + red[1] + red[2] + red[3];
}

// K5: reduce 2048 partials -> loss.
__global__ void k5_loss(const float* __restrict__ partial, float* __restrict__ out_loss) {
  int t = threadIdx.x;                 // 256 threads
  float s = 0.f;
#pragma unroll
  for (int i = 0; i < 8; ++i) s += partial[t + i * 256];
#pragma unroll
  for (int off = 32; off > 0; off >>= 1) s += __shfl_down(s, off);
  __shared__ float red[4];
  int lane = t & 63, w = t >> 6;
  if (lane == 0) red[w] = s;
  __syncthreads();
  if (t == 0) out_loss[0] = (red[0] + red[1] + red[2] + red[3]) * (1.0f / 2097152.0f);
}

extern "C" void kernel_launch(void* const* d_in, const int* in_sizes, int n_in,
                              void* d_out, int out_size, void* d_ws, size_t ws_size,
                              hipStream_t stream) {
  const float* x = (const float*)d_in[0];
  const float* E = (const float*)d_in[1];

  float* ws    = (float*)d_ws;
  float* Et    = ws + WS_ET;
  float* h     = ws + WS_H;
  float* part  = ws + WS_PART;
  float* pbest = ws + WS_PBEST;
  unsigned short* pidx = (unsigned short*)(ws + WS_PIDX);

  float* out      = (float*)d_out;
  float* out_q    = out;                      // 2097152
  float* out_enc  = out + 2097152;            // 33554432
  float* out_ind  = out + 35651584;           // 32768
  float* out_loss = out + 35684352;           // 1

  k1_prep<<<4, 256, 0, stream>>>(E, Et, h);
  k2_score<<<512, 256, 0, stream>>>(x, Et, h, pbest, pidx);
  k34_fused<<<2048, 256, 0, stream>>>(x, Et, pbest, pidx, part, out_q, out_enc, out_ind);
  k5_loss<<<1, 256, 0, stream>>>(part, out_loss);
}

// Round 8
// 236.898 us; speedup vs baseline: 1.1170x; 1.1170x over previous
//
#include <hip/hip_runtime.h>
#include <hip/hip_bf16.h>

// Problem: B=8, T=4096, D=64, K=1024. N = B*T = 32768 rows.
// Inputs:  d_in[0] = x (f32, 2097152), d_in[1] = embeddings (f32, [D][K] = 64x1024)
// Output: FLOAT32, concatenated in return order:
//   quantized (2097152) | encodings (33554432) | indices (32768) | loss (1)

#define NROWS 32768
#define DDIM  64
#define KCB   1024
#define NSEG  8
#define SEG   128        // codes per K-segment

typedef float f32x4 __attribute__((ext_vector_type(4)));

// ws layout (float index):
#define WS_ET    0        // Et [K][D] transposed embeddings (65536 f32)
#define WS_H     65536    // 0.5*||e_k||^2 (1024)
#define WS_PART  66560    // per-block loss partials (2048 f32)
#define WS_PBEST 68608    // per-(seg,row) best score (8*32768 f32)
#define WS_PIDX  330752   // per-(seg,row) best index (8*32768 u16 = 131072 f32)
// end: 461824 f32 = 1.85 MB

// K1: transpose E (D,K) -> Et (K,D), h[k] = 0.5*||e_k||^2.
__global__ __launch_bounds__(256) void k1_prep(const float* __restrict__ E,
                                               float* __restrict__ Et,
                                               float* __restrict__ h) {
  int k = blockIdx.x * 256 + threadIdx.x;   // 0..1023
  float col[DDIM];
  float sum = 0.f;
#pragma unroll
  for (int d = 0; d < DDIM; ++d) {
    float v = E[d * KCB + k];               // coalesced across lanes
    col[d] = v;
    sum = fmaf(v, v, sum);
  }
  float4* dst = (float4*)(Et + (size_t)k * DDIM);
#pragma unroll
  for (int i = 0; i < 16; ++i)
    dst[i] = make_float4(col[4*i], col[4*i+1], col[4*i+2], col[4*i+3]);
  h[k] = 0.5f * sum;
}

// K2: per (row, K-segment) partial argmax of score = x.e_k - 0.5||e_k||^2.
// E-segment in LDS (32KB, uniform broadcast reads). x row pinned in 64 VGPRs
// via opaque asm outputs ("+v"): LLVM cannot rematerialize an inline-asm
// result, so the loads CANNOT be sunk into the K-loop (the r5/r6/r7 failure).
__global__ __launch_bounds__(256, 3) void k2_score(const float* __restrict__ x,
                                                   const float* __restrict__ Et,
                                                   const float* __restrict__ h,
                                                   float* __restrict__ pbest,
                                                   unsigned short* __restrict__ pidx) {
  __shared__ float se[SEG * DDIM];   // 32 KB E-tile [k][d]
  __shared__ float sh[SEG];

  int bid = blockIdx.x;              // 0..1023
  int ks  = bid >> 7;                // segment 0..7 (128 consecutive blocks share seg)
  int tid = threadIdx.x;
  int n   = (bid & 127) * 256 + tid;

  // cooperative stage: 2048 float4, 8 per thread, coalesced
  {
    const float4* src = (const float4*)(Et + (size_t)ks * SEG * DDIM);
    float4* dst = (float4*)se;
#pragma unroll
    for (int i = 0; i < 8; ++i) dst[tid + i * 256] = src[tid + i * 256];
    if (tid < SEG) sh[tid] = h[ks * SEG + tid];
  }

  // x row -> 64 VGPRs, then make each value an opaque asm output (non-remat).
  const float4* xr = (const float4*)(x + (size_t)n * DDIM);
  float4 xv[16];
#pragma unroll
  for (int i = 0; i < 16; ++i) xv[i] = xr[i];
#pragma unroll
  for (int i = 0; i < 16; ++i)
    asm volatile("" : "+v"(xv[i].x), "+v"(xv[i].y), "+v"(xv[i].z), "+v"(xv[i].w));
  __syncthreads();

  float best = -3.0e38f;
  int besti = ks * SEG;

#pragma unroll 1
  for (int kg = 0; kg < SEG; kg += 8) {
    float acc[8];
#pragma unroll
    for (int j = 0; j < 8; ++j) acc[j] = -sh[kg + j];
#pragma unroll
    for (int i = 0; i < 16; ++i) {
      float4 xi = xv[i];
#pragma unroll
      for (int j = 0; j < 8; ++j) {
        float4 e4 = *(const float4*)(se + (kg + j) * DDIM + i * 4);  // uniform broadcast
        acc[j] = fmaf(xi.x, e4.x, acc[j]);
        acc[j] = fmaf(xi.y, e4.y, acc[j]);
        acc[j] = fmaf(xi.z, e4.z, acc[j]);
        acc[j] = fmaf(xi.w, e4.w, acc[j]);
      }
    }
#pragma unroll
    for (int j = 0; j < 8; ++j) {
      if (acc[j] > best) { best = acc[j]; besti = ks * SEG + kg + j; }  // strict >: first wins
    }
  }
  pbest[ks * NROWS + n] = best;
  pidx [ks * NROWS + n] = (unsigned short)besti;
}

// K34 fused: combine segments -> index (16 rows/block); indices, quantized
// (1 float4/thread, coalesced), loss partial (plain store), one-hot stream.
__global__ __launch_bounds__(256) void k34_fused(const float* __restrict__ x,
                                                 const float* __restrict__ Et,
                                                 const float* __restrict__ pbest,
                                                 const unsigned short* __restrict__ pidx,
                                                 float* __restrict__ partial,
                                                 float* __restrict__ out_q,
                                                 float* __restrict__ out_enc,
                                                 float* __restrict__ out_ind) {
  __shared__ int sidx[16];
  int tid = threadIdx.x;
  int r0 = blockIdx.x * 16;

  if (tid < 16) {
    int n = r0 + tid;
    float best = pbest[n];
    int bi = pidx[n];
#pragma unroll
    for (int q = 1; q < NSEG; ++q) {          // ascending segs: first-occurrence ties
      float b = pbest[q * NROWS + n];
      int i2 = (int)pidx[q * NROWS + n];
      if (b > best) { best = b; bi = i2; }
    }
    sidx[tid] = bi;
    out_ind[n] = (float)bi;
  }
  __syncthreads();

  // quantized gather + loss: thread covers row r0+(tid>>4), dims [4*(tid&15), +4)
  int r = tid >> 4, c = tid & 15;
  int n = r0 + r;
  int bi = sidx[r];
  float4 q4 = *(const float4*)(Et + (size_t)bi * DDIM + c * 4);   // L2-resident gather
  float4 x4 = *(const float4*)(x + (size_t)n * DDIM + c * 4);     // coalesced
  float d0 = q4.x - x4.x, d1 = q4.y - x4.y, d2 = q4.z - x4.z, d3 = q4.w - x4.w;
  float lsum = 0.f;
  lsum = fmaf(d0, d0, lsum); lsum = fmaf(d1, d1, lsum);
  lsum = fmaf(d2, d2, lsum); lsum = fmaf(d3, d3, lsum);
  *(float4*)(out_q + (size_t)n * DDIM + c * 4) = q4;

  // one-hot encodings: thread t covers cols [4t, 4t+4) of each of 16 rows
#pragma unroll
  for (int rr = 0; rr < 16; ++rr) {
    int bk = sidx[rr];
    f32x4 v = (f32x4)(0.f);
    if ((bk >> 2) == tid) v[bk & 3] = 1.0f;
    __builtin_nontemporal_store(v, (f32x4*)(out_enc + (size_t)(r0 + rr) * KCB + tid * 4));
  }

  // block loss reduction -> plain store
#pragma unroll
  for (int off = 32; off > 0; off >>= 1) lsum += __shfl_down(lsum, off);
  __shared__ float red[4];
  int lane = tid & 63, w = tid >> 6;
  if (lane == 0) red[w] = lsum;
  __syncthreads();
  if (tid == 0) partial[blockIdx.x] = red[0] + red[1] + red[2] + red[3];
}

// K5: reduce 2048 partials -> loss.
__global__ void k5_loss(const float* __restrict__ partial, float* __restrict__ out_loss) {
  int t = threadIdx.x;                 // 256 threads
  float s = 0.f;
#pragma unroll
  for (int i = 0; i < 8; ++i) s += partial[t + i * 256];
#pragma unroll
  for (int off = 32; off > 0; off >>= 1) s += __shfl_down(s, off);
  __shared__ float red[4];
  int lane = t & 63, w = t >> 6;
  if (lane == 0) red[w] = s;
  __syncthreads();
  if (t == 0) out_loss[0] = (red[0] + red[1] + red[2] + red[3]) * (1.0f / 2097152.0f);
}

extern "C" void kernel_launch(void* const* d_in, const int* in_sizes, int n_in,
                              void* d_out, int out_size, void* d_ws, size_t ws_size,
                              hipStream_t stream) {
  const float* x = (const float*)d_in[0];
  const float* E = (const float*)d_in[1];

  float* ws    = (float*)d_ws;
  float* Et    = ws + WS_ET;
  float* h     = ws + WS_H;
  float* part  = ws + WS_PART;
  float* pbest = ws + WS_PBEST;
  unsigned short* pidx = (unsigned short*)(ws + WS_PIDX);

  float* out      = (float*)d_out;
  float* out_q    = out;                      // 2097152
  float* out_enc  = out + 2097152;            // 33554432
  float* out_ind  = out + 35651584;           // 32768
  float* out_loss = out + 35684352;           // 1

  k1_prep<<<4, 256, 0, stream>>>(E, Et, h);
  k2_score<<<1024, 256, 0, stream>>>(x, Et, h, pbest, pidx);
  k34_fused<<<2048, 256, 0, stream>>>(x, Et, pbest, pidx, part, out_q, out_enc, out_ind);
  k5_loss<<<1, 256, 0, stream>>>(part, out_loss);
}